// Round 8
// baseline (187.018 us; speedup 1.0000x reference)
//
#include <hip/hip_runtime.h>
#include <math.h>

#define D_MODEL 1024
#define SEQ     2048
#define BATCH   4
#define NROWS   (BATCH * SEQ)   // 8192

typedef short bf16x8 __attribute__((ext_vector_type(8)));
typedef float f32x4  __attribute__((ext_vector_type(4)));

// f32 -> bf16 round-to-nearest-even
static __device__ __forceinline__ unsigned short f2bf(float f) {
    unsigned int x = __float_as_uint(f);
    x += 0x7FFFu + ((x >> 16) & 1u);
    return (unsigned short)(x >> 16);
}

// ---------------------------------------------------------------------------
// Kernel 1: pack W -> Wb[192][1024] bf16, coalesced reads + LDS transpose.
// grid 48 = 3 matrices x 16 k-tiles of 64.
// ---------------------------------------------------------------------------
__global__ __launch_bounds__(256) void w_pack(
    const float* __restrict__ Wq, const float* __restrict__ Wk,
    const float* __restrict__ Wv, unsigned short* __restrict__ Wb)
{
    __shared__ float st[64][68];
    const int mat = blockIdx.x >> 4;
    const int k0  = (blockIdx.x & 15) * 64;
    const float* W = (mat == 0) ? Wq : (mat == 1) ? Wk : Wv;
    const int t  = threadIdx.x;
    const int kr = t >> 2, cs = (t & 3) * 16;
#pragma unroll
    for (int i = 0; i < 4; ++i)
        *(float4*)&st[kr][cs + i * 4] = *(const float4*)&W[(size_t)(k0 + kr) * 64 + cs + i * 4];
    __syncthreads();
    const int c = t >> 2, ks = (t & 3) * 16;
    unsigned short tmp[16];
#pragma unroll
    for (int j = 0; j < 16; ++j) tmp[j] = f2bf(st[ks + j][c]);
    *(uint4*)&Wb[(size_t)(mat * 64 + c) * D_MODEL + k0 + ks]     = *(uint4*)&tmp[0];
    *(uint4*)&Wb[(size_t)(mat * 64 + c) * D_MODEL + k0 + ks + 8] = *(uint4*)&tmp[8];
}

// ---------------------------------------------------------------------------
// Kernel 2: QKV projection via MFMA.  BM=16, BN=96, BK=64.
// grid (512 row-tiles, 2 col-blocks) x 128 thr (2 waves, 48 cols each)
// -> 4 blocks/CU: barrier drains overlap across independent blocks.
// ---------------------------------------------------------------------------
__global__ __launch_bounds__(128) void qkv_proj_mfma(
    const float* __restrict__ x, const unsigned short* __restrict__ Wb,
    const float* __restrict__ bq, const float* __restrict__ bk,
    const float* __restrict__ bv,
    unsigned short* __restrict__ qb, unsigned short* __restrict__ kb,
    unsigned short* __restrict__ Vt)
{
    __shared__ unsigned short A_lds[16 * 72];
    __shared__ unsigned short B_lds[96 * 72];

    const int tid  = threadIdx.x;
    const int lane = tid & 63;
    const int wn   = tid >> 6;        // 0..1
    const int lg   = lane >> 4;       // 0..3
    const int lc   = lane & 15;       // 0..15
    const int m0   = blockIdx.x * 16;
    const int n0   = blockIdx.y * 96;

    f32x4 acc[3];
#pragma unroll
    for (int nf = 0; nf < 3; ++nf) acc[nf] = (f32x4){0.f, 0.f, 0.f, 0.f};

    const int arow = tid >> 3, asp = tid & 7;   // A: 16 rows x 8 slots
    float4 areg0, areg1;
    uint4  breg[6];                             // B: 96 rows x 8 slots / 128 thr

    {   // prologue: K-iter 0
        const float* ap = &x[(size_t)(m0 + arow) * D_MODEL + asp * 8];
        areg0 = *(const float4*)ap;
        areg1 = *(const float4*)(ap + 4);
#pragma unroll
        for (int i = 0; i < 6; ++i) {
            int c = tid + 128 * i, brow = c >> 3, bsp = c & 7;
            breg[i] = *(const uint4*)&Wb[(size_t)(n0 + brow) * D_MODEL + bsp * 8];
        }
    }

    for (int it = 0; it < 16; ++it) {
        __syncthreads();
        {
            unsigned int a0 = f2bf(areg0.x) | ((unsigned)f2bf(areg0.y) << 16);
            unsigned int a1 = f2bf(areg0.z) | ((unsigned)f2bf(areg0.w) << 16);
            unsigned int a2 = f2bf(areg1.x) | ((unsigned)f2bf(areg1.y) << 16);
            unsigned int a3 = f2bf(areg1.z) | ((unsigned)f2bf(areg1.w) << 16);
            *(uint4*)&A_lds[arow * 72 + asp * 8] = make_uint4(a0, a1, a2, a3);
#pragma unroll
            for (int i = 0; i < 6; ++i) {
                int c = tid + 128 * i, brow = c >> 3, bsp = c & 7;
                *(uint4*)&B_lds[brow * 72 + bsp * 8] = breg[i];
            }
        }
        if (it < 15) {
            int k0 = (it + 1) * 64;
            const float* ap = &x[(size_t)(m0 + arow) * D_MODEL + k0 + asp * 8];
            areg0 = *(const float4*)ap;
            areg1 = *(const float4*)(ap + 4);
#pragma unroll
            for (int i = 0; i < 6; ++i) {
                int c = tid + 128 * i, brow = c >> 3, bsp = c & 7;
                breg[i] = *(const uint4*)&Wb[(size_t)(n0 + brow) * D_MODEL + k0 + bsp * 8];
            }
        }
        __syncthreads();
#pragma unroll
        for (int kk = 0; kk < 2; ++kk) {
            bf16x8 af = *(const bf16x8*)&A_lds[lc * 72 + kk * 32 + lg * 8];
#pragma unroll
            for (int nf = 0; nf < 3; ++nf) {
                bf16x8 bf = *(const bf16x8*)&B_lds[(wn * 48 + nf * 16 + lc) * 72 + kk * 32 + lg * 8];
                acc[nf] = __builtin_amdgcn_mfma_f32_16x16x32_bf16(af, bf, acc[nf], 0, 0, 0);
            }
        }
    }

    // epilogue: D-frag col = lane&15, row = lg*4 + r
#pragma unroll
    for (int nf = 0; nf < 3; ++nf) {
        int col = n0 + wn * 48 + nf * 16 + lc;
        int mat = col >> 6, cc = col & 63;
        int grow0 = m0 + lg * 4;
        if (mat == 0) {
            float bias = bq[cc];
#pragma unroll
            for (int r = 0; r < 4; ++r)
                qb[(size_t)(grow0 + r) * 64 + cc] = f2bf((acc[nf][r] + bias) * 0.125f);
        } else if (mat == 1) {
            float bias = bk[cc];
#pragma unroll
            for (int r = 0; r < 4; ++r)
                kb[(size_t)(grow0 + r) * 64 + cc] = f2bf(acc[nf][r] + bias);
        } else {
            float bias = bv[cc];
            int bb = grow0 >> 11, seq = grow0 & 2047;
            ushort4 pk;
            pk.x = f2bf(acc[nf][0] + bias);
            pk.y = f2bf(acc[nf][1] + bias);
            pk.z = f2bf(acc[nf][2] + bias);
            pk.w = f2bf(acc[nf][3] + bias);
            *(ushort4*)&Vt[((size_t)bb * 64 + cc) * SEQ + seq] = pk;
        }
    }
}

// ---------------------------------------------------------------------------
// Kernel 3: causal flash attention partials — SINGLE WAVE per block, NO
// barriers, NO K/V LDS (K/V are L2-resident; MFMA frags loaded per-lane
// direct from global). P relayout via small same-wave LDS.
// grid (qt 0..127 [16 q-rows], ch 0..3 [512 keys], b 0..3), 64 thr.
// ---------------------------------------------------------------------------
__global__ __launch_bounds__(64) void attn_partial(
    const unsigned short* __restrict__ qb, const unsigned short* __restrict__ kb,
    const unsigned short* __restrict__ Vt,
    float* __restrict__ O_part, float* __restrict__ ml)
{
    __shared__ unsigned short P_lds[16 * 72];

    const int qt = blockIdx.x;
    const int ch = blockIdx.y;
    const int b  = blockIdx.z;
    const int lane = threadIdx.x;
    const int lg = lane >> 4, lc = lane & 15;

    int nt = ((qt * 16 + 15 - ch * 512) >> 6) + 1;
    if (nt > 8) nt = 8;
    if (nt <= 0) return;                       // block-uniform exit

    const size_t qrow = (size_t)(b * SEQ + qt * 16 + lc);
    bf16x8 qf0 = *(const bf16x8*)&qb[qrow * 64 + lg * 8];
    bf16x8 qf1 = *(const bf16x8*)&qb[qrow * 64 + 32 + lg * 8];

    f32x4 O[4];
#pragma unroll
    for (int df = 0; df < 4; ++df) O[df] = (f32x4){0.f, 0.f, 0.f, 0.f};
    float m[4] = {-1e30f, -1e30f, -1e30f, -1e30f};
    float l[4] = {0.f, 0.f, 0.f, 0.f};

    const int rowbase = qt * 16 + lg * 4;

    for (int t = 0; t < nt; ++t) {
        const int kb0 = ch * 512 + t * 64;

        // QK^T: K frags direct from global (B-frag: row=key local, k=lg*8+j)
        f32x4 s[4];
#pragma unroll
        for (int kf = 0; kf < 4; ++kf) {
            const unsigned short* kp = &kb[((size_t)(b * SEQ + kb0 + kf * 16 + lc)) * 64];
            bf16x8 k0 = *(const bf16x8*)&kp[lg * 8];
            bf16x8 k1 = *(const bf16x8*)&kp[32 + lg * 8];
            f32x4 z = (f32x4){0.f, 0.f, 0.f, 0.f};
            z = __builtin_amdgcn_mfma_f32_16x16x32_bf16(qf0, k0, z, 0, 0, 0);
            s[kf] = __builtin_amdgcn_mfma_f32_16x16x32_bf16(qf1, k1, z, 0, 0, 0);
        }

        // online softmax; D-layout: key = kb0 + kf*16 + lc, row = rowbase + r
#pragma unroll
        for (int r = 0; r < 4; ++r) {
            float tm = -1e30f;
#pragma unroll
            for (int kf = 0; kf < 4; ++kf) {
                float sv = s[kf][r];
                if (kb0 + kf * 16 + lc > rowbase + r) sv = -1e30f;
                s[kf][r] = sv;
                tm = fmaxf(tm, sv);
            }
            tm = fmaxf(tm, __shfl_xor(tm, 1));
            tm = fmaxf(tm, __shfl_xor(tm, 2));
            tm = fmaxf(tm, __shfl_xor(tm, 4));
            tm = fmaxf(tm, __shfl_xor(tm, 8));
            float mn  = fmaxf(m[r], tm);
            float fac = __expf(m[r] - mn);
            float ts  = 0.f;
#pragma unroll
            for (int kf = 0; kf < 4; ++kf) {
                float p = __expf(s[kf][r] - mn);
                ts += p;
                P_lds[(lg * 4 + r) * 72 + kf * 16 + lc] = f2bf(p);
            }
            ts += __shfl_xor(ts, 1);
            ts += __shfl_xor(ts, 2);
            ts += __shfl_xor(ts, 4);
            ts += __shfl_xor(ts, 8);
            l[r] = l[r] * fac + ts;
            m[r] = mn;
            O[0][r] *= fac; O[1][r] *= fac; O[2][r] *= fac; O[3][r] *= fac;
        }

        // PV: P frags from LDS (same-wave, lgkmcnt-ordered), V direct global
        bf16x8 pf0 = *(const bf16x8*)&P_lds[lc * 72 + lg * 8];
        bf16x8 pf1 = *(const bf16x8*)&P_lds[lc * 72 + 32 + lg * 8];
#pragma unroll
        for (int df = 0; df < 4; ++df) {
            const unsigned short* vp = &Vt[((size_t)(b * 64 + df * 16 + lc)) * SEQ + kb0];
            bf16x8 v0 = *(const bf16x8*)&vp[lg * 8];
            bf16x8 v1 = *(const bf16x8*)&vp[32 + lg * 8];
            O[df] = __builtin_amdgcn_mfma_f32_16x16x32_bf16(pf0, v0, O[df], 0, 0, 0);
            O[df] = __builtin_amdgcn_mfma_f32_16x16x32_bf16(pf1, v1, O[df], 0, 0, 0);
        }
    }

    const int slot = (b * 128 + qt) * 4 + ch;
    float* Op = O_part + (size_t)slot * 1024;
#pragma unroll
    for (int df = 0; df < 4; ++df)
#pragma unroll
        for (int r = 0; r < 4; ++r)
            Op[(lg * 4 + r) * 64 + df * 16 + lc] = O[df][r];
    if (lc == 0) {
#pragma unroll
        for (int r = 0; r < 4; ++r) {
            ml[slot * 32 + lg * 4 + r]      = m[r];
            ml[slot * 32 + 16 + lg * 4 + r] = l[r];
        }
    }
}

// ---------------------------------------------------------------------------
// Kernel 4: merge chunk partials -> final output (f32).
// ---------------------------------------------------------------------------
__global__ __launch_bounds__(256) void attn_merge(
    const float* __restrict__ O_part, const float* __restrict__ ml,
    float* __restrict__ out)
{
    int idx = blockIdx.x * 256 + threadIdx.x;   // 262144 threads, 2 f32 each
    int row = idx >> 5;
    int d0  = (idx & 31) * 2;
    int b = row >> 11, seq = row & 2047;
    int qt = seq >> 4, rl = seq & 15;
    int nc = ((qt * 16 + 15) >> 9) + 1;         // active chunks, 1..4
    int sb = (b * 128 + qt) * 4;

    float M = -1e30f;
    for (int c = 0; c < nc; ++c) M = fmaxf(M, ml[(sb + c) * 32 + rl]);
    float L = 0.f, o0 = 0.f, o1 = 0.f;
    for (int c = 0; c < nc; ++c) {
        float e = __expf(ml[(sb + c) * 32 + rl] - M);
        L += e * ml[(sb + c) * 32 + 16 + rl];
        const float* Op = O_part + (size_t)(sb + c) * 1024 + rl * 64 + d0;
        o0 += e * Op[0];
        o1 += e * Op[1];
    }
    float inv = 1.f / L;
    *(float2*)&out[(size_t)row * 64 + d0] = make_float2(o0 * inv, o1 * inv);
}

// ---------------------------------------------------------------------------
extern "C" void kernel_launch(void* const* d_in, const int* in_sizes, int n_in,
                              void* d_out, int out_size, void* d_ws, size_t ws_size,
                              hipStream_t stream)
{
    (void)in_sizes; (void)n_in; (void)out_size; (void)ws_size;

    const float* x  = (const float*)d_in[0];
    const float* Wq = (const float*)d_in[1];
    const float* bq = (const float*)d_in[2];
    const float* Wk = (const float*)d_in[3];
    const float* bk = (const float*)d_in[4];
    const float* Wv = (const float*)d_in[5];
    const float* bv = (const float*)d_in[6];
    float* out = (float*)d_out;

    // workspace layout (bytes):
    // Wb 393216 | qb 1M | kb 1M | Vt 1M | ml 262144 | O_part 8M  (~12.2 MB)
    char* ws = (char*)d_ws;
    unsigned short* Wb = (unsigned short*)(ws);
    unsigned short* qb = (unsigned short*)(ws + 393216);
    unsigned short* kb = (unsigned short*)(ws + 393216 + 1048576);
    unsigned short* Vt = (unsigned short*)(ws + 393216 + 2 * 1048576);
    float*          ml = (float*)(ws + 393216 + 3 * 1048576);
    float*      O_part = (float*)(ws + 393216 + 3 * 1048576 + 262144);

    w_pack<<<48, 256, 0, stream>>>(Wq, Wk, Wv, Wb);
    qkv_proj_mfma<<<dim3(512, 2), 128, 0, stream>>>(x, Wb, bq, bk, bv, qb, kb, Vt);
    attn_partial<<<dim3(128, 4, 4), 64, 0, stream>>>(qb, kb, Vt, O_part, ml);
    attn_merge<<<1024, 256, 0, stream>>>(O_part, ml, out);
}

// Round 9
// 161.978 us; speedup vs baseline: 1.1546x; 1.1546x over previous
//
#include <hip/hip_runtime.h>
#include <math.h>

#define D_MODEL 1024
#define SEQ     2048
#define BATCH   4
#define NROWS   (BATCH * SEQ)   // 8192

typedef short bf16x8 __attribute__((ext_vector_type(8)));
typedef float f32x4  __attribute__((ext_vector_type(4)));

// f32 -> bf16 round-to-nearest-even
static __device__ __forceinline__ unsigned short f2bf(float f) {
    unsigned int x = __float_as_uint(f);
    x += 0x7FFFu + ((x >> 16) & 1u);
    return (unsigned short)(x >> 16);
}

// ---------------------------------------------------------------------------
// Kernel 1: pack W -> Wb[192][1024] bf16, coalesced reads + LDS transpose.
// ---------------------------------------------------------------------------
__global__ __launch_bounds__(256) void w_pack(
    const float* __restrict__ Wq, const float* __restrict__ Wk,
    const float* __restrict__ Wv, unsigned short* __restrict__ Wb)
{
    __shared__ float st[64][68];
    const int mat = blockIdx.x >> 4;
    const int k0  = (blockIdx.x & 15) * 64;
    const float* W = (mat == 0) ? Wq : (mat == 1) ? Wk : Wv;
    const int t  = threadIdx.x;
    const int kr = t >> 2, cs = (t & 3) * 16;
#pragma unroll
    for (int i = 0; i < 4; ++i)
        *(float4*)&st[kr][cs + i * 4] = *(const float4*)&W[(size_t)(k0 + kr) * 64 + cs + i * 4];
    __syncthreads();
    const int c = t >> 2, ks = (t & 3) * 16;
    unsigned short tmp[16];
#pragma unroll
    for (int j = 0; j < 16; ++j) tmp[j] = f2bf(st[ks + j][c]);
    *(uint4*)&Wb[(size_t)(mat * 64 + c) * D_MODEL + k0 + ks]     = *(uint4*)&tmp[0];
    *(uint4*)&Wb[(size_t)(mat * 64 + c) * D_MODEL + k0 + ks + 8] = *(uint4*)&tmp[8];
}

// ---------------------------------------------------------------------------
// Kernel 2: QKV projection — BARRIER-FREE, LDS-free main loop.
// grid 512 x 192 thr (3 waves). Block owns 16 rows; wave wv owns matrix wv
// (64 cols). Per k-step each lane builds A-frag direct from x (f32->bf16 in
// regs) and 4 B-frags direct from Wb. No __syncthreads anywhere -> compiler
// pipelines loads across k-steps. Epilogue: same-wave LDS transpose so
// global stores are dense 32B/lane.
// ---------------------------------------------------------------------------
__global__ __launch_bounds__(192) void qkv_proj_mfma(
    const float* __restrict__ x, const unsigned short* __restrict__ Wb,
    const float* __restrict__ bq, const float* __restrict__ bk,
    const float* __restrict__ bv,
    unsigned short* __restrict__ qb, unsigned short* __restrict__ kb,
    unsigned short* __restrict__ Vt)
{
    __shared__ float stage[3][1088];

    const int tid  = threadIdx.x;
    const int wv   = tid >> 6;        // 0:q 1:k 2:v
    const int lane = tid & 63;
    const int lg   = lane >> 4;       // 0..3
    const int lc   = lane & 15;       // 0..15
    const int m0   = blockIdx.x * 16;
    const int n0w  = wv * 64;

    f32x4 acc[4];
#pragma unroll
    for (int nf = 0; nf < 4; ++nf) acc[nf] = (f32x4){0.f, 0.f, 0.f, 0.f};

    const float* ax = &x[(size_t)(m0 + lc) * D_MODEL + lg * 8];

#pragma unroll 4
    for (int ks = 0; ks < 32; ++ks) {
        float4 a0 = *(const float4*)(ax + ks * 32);
        float4 a1 = *(const float4*)(ax + ks * 32 + 4);
        bf16x8 af;
        af[0] = (short)f2bf(a0.x); af[1] = (short)f2bf(a0.y);
        af[2] = (short)f2bf(a0.z); af[3] = (short)f2bf(a0.w);
        af[4] = (short)f2bf(a1.x); af[5] = (short)f2bf(a1.y);
        af[6] = (short)f2bf(a1.z); af[7] = (short)f2bf(a1.w);
#pragma unroll
        for (int nf = 0; nf < 4; ++nf) {
            bf16x8 bf = *(const bf16x8*)&Wb[(size_t)(n0w + nf * 16 + lc) * D_MODEL + ks * 32 + lg * 8];
            acc[nf] = __builtin_amdgcn_mfma_f32_16x16x32_bf16(af, bf, acc[nf], 0, 0, 0);
        }
    }

    // ---- epilogue: same-wave LDS transpose -> dense stores ----
    float* st = stage[wv];
    if (wv < 2) {
        const float* bias = (wv == 0) ? bq : bk;
        const float scale = (wv == 0) ? 0.125f : 1.0f;
        // D-frag: row = lg*4+r, col = nf*16+lc
#pragma unroll
        for (int nf = 0; nf < 4; ++nf) {
            float bs = bias[nf * 16 + lc];
#pragma unroll
            for (int r = 0; r < 4; ++r)
                st[(lg * 4 + r) * 68 + nf * 16 + lc] = (acc[nf][r] + bs) * scale;
        }
        // read back: lane owns row lane&15, 16 cols starting (lane>>4)*16
        unsigned short tmp[16];
        const int rr = lane & 15, cc0 = (lane >> 4) * 16;
#pragma unroll
        for (int j = 0; j < 16; ++j) tmp[j] = f2bf(st[rr * 68 + cc0 + j]);
        unsigned short* op = (wv == 0) ? qb : kb;
        unsigned short* dst = &op[(size_t)(m0 + rr) * 64 + cc0];
        *(uint4*)dst       = *(uint4*)&tmp[0];
        *(uint4*)(dst + 8) = *(uint4*)&tmp[8];
    } else {
        // V transposed: stage [d 64][seq 16 pad17]
#pragma unroll
        for (int nf = 0; nf < 4; ++nf) {
            float bs = bv[nf * 16 + lc];
#pragma unroll
            for (int r = 0; r < 4; ++r)
                st[(nf * 16 + lc) * 17 + lg * 4 + r] = acc[nf][r] + bs;
        }
        unsigned short tmp[16];
#pragma unroll
        for (int j = 0; j < 16; ++j) tmp[j] = f2bf(st[lane * 17 + j]);
        const int bb = m0 >> 11, seq = m0 & 2047;
        unsigned short* dst = &Vt[((size_t)(bb * 64 + lane)) * SEQ + seq];
        *(uint4*)dst       = *(uint4*)&tmp[0];
        *(uint4*)(dst + 8) = *(uint4*)&tmp[8];
    }
}

// ---------------------------------------------------------------------------
// Kernel 3: causal flash attention partials — single wave, no barriers,
// direct-global K/V frags with CROSS-TILE PREFETCH (K[t+1] issued after
// QK^T[t]; V[t+1] after PV[t] -> latency hides under adjacent phases).
// grid (qt 0..127, ch 0..3, b 0..3), 64 thr.
// ---------------------------------------------------------------------------
__global__ __launch_bounds__(64) void attn_partial(
    const unsigned short* __restrict__ qb, const unsigned short* __restrict__ kb,
    const unsigned short* __restrict__ Vt,
    float* __restrict__ O_part, float* __restrict__ ml)
{
    __shared__ unsigned short P_lds[16 * 72];

    const int qt = blockIdx.x;
    const int ch = blockIdx.y;
    const int b  = blockIdx.z;
    const int lane = threadIdx.x;
    const int lg = lane >> 4, lc = lane & 15;

    int nt = ((qt * 16 + 15 - ch * 512) >> 6) + 1;
    if (nt > 8) nt = 8;
    if (nt <= 0) return;                       // block-uniform exit

    const size_t qrow = (size_t)(b * SEQ + qt * 16 + lc);
    bf16x8 qf0 = *(const bf16x8*)&qb[qrow * 64 + lg * 8];
    bf16x8 qf1 = *(const bf16x8*)&qb[qrow * 64 + 32 + lg * 8];

    f32x4 O[4];
#pragma unroll
    for (int df = 0; df < 4; ++df) O[df] = (f32x4){0.f, 0.f, 0.f, 0.f};
    float m[4] = {-1e30f, -1e30f, -1e30f, -1e30f};
    float l[4] = {0.f, 0.f, 0.f, 0.f};

    const int rowbase = qt * 16 + lg * 4;

    bf16x8 kr[8], vr[8];
    {   // prologue: tile 0 K+V
        const int kb0 = ch * 512;
#pragma unroll
        for (int kf = 0; kf < 4; ++kf) {
            const unsigned short* kp = &kb[((size_t)(b * SEQ + kb0 + kf * 16 + lc)) * 64];
            kr[kf * 2]     = *(const bf16x8*)&kp[lg * 8];
            kr[kf * 2 + 1] = *(const bf16x8*)&kp[32 + lg * 8];
            const unsigned short* vp = &Vt[((size_t)(b * 64 + kf * 16 + lc)) * SEQ + kb0];
            vr[kf * 2]     = *(const bf16x8*)&vp[lg * 8];
            vr[kf * 2 + 1] = *(const bf16x8*)&vp[32 + lg * 8];
        }
    }

    for (int t = 0; t < nt; ++t) {
        const int kb0 = ch * 512 + t * 64;

        // QK^T from kr
        f32x4 s[4];
#pragma unroll
        for (int kf = 0; kf < 4; ++kf) {
            f32x4 z = (f32x4){0.f, 0.f, 0.f, 0.f};
            z = __builtin_amdgcn_mfma_f32_16x16x32_bf16(qf0, kr[kf * 2], z, 0, 0, 0);
            s[kf] = __builtin_amdgcn_mfma_f32_16x16x32_bf16(qf1, kr[kf * 2 + 1], z, 0, 0, 0);
        }
        // prefetch K for t+1 (hides under softmax + PV)
        if (t + 1 < nt) {
            const int kb0n = kb0 + 64;
#pragma unroll
            for (int kf = 0; kf < 4; ++kf) {
                const unsigned short* kp = &kb[((size_t)(b * SEQ + kb0n + kf * 16 + lc)) * 64];
                kr[kf * 2]     = *(const bf16x8*)&kp[lg * 8];
                kr[kf * 2 + 1] = *(const bf16x8*)&kp[32 + lg * 8];
            }
        }

        // online softmax; D-layout: key = kb0 + kf*16 + lc, row = rowbase + r
#pragma unroll
        for (int r = 0; r < 4; ++r) {
            float tm = -1e30f;
#pragma unroll
            for (int kf = 0; kf < 4; ++kf) {
                float sv = s[kf][r];
                if (kb0 + kf * 16 + lc > rowbase + r) sv = -1e30f;
                s[kf][r] = sv;
                tm = fmaxf(tm, sv);
            }
            tm = fmaxf(tm, __shfl_xor(tm, 1));
            tm = fmaxf(tm, __shfl_xor(tm, 2));
            tm = fmaxf(tm, __shfl_xor(tm, 4));
            tm = fmaxf(tm, __shfl_xor(tm, 8));
            float mn  = fmaxf(m[r], tm);
            float fac = __expf(m[r] - mn);
            float ts  = 0.f;
#pragma unroll
            for (int kf = 0; kf < 4; ++kf) {
                float p = __expf(s[kf][r] - mn);
                ts += p;
                P_lds[(lg * 4 + r) * 72 + kf * 16 + lc] = f2bf(p);
            }
            ts += __shfl_xor(ts, 1);
            ts += __shfl_xor(ts, 2);
            ts += __shfl_xor(ts, 4);
            ts += __shfl_xor(ts, 8);
            l[r] = l[r] * fac + ts;
            m[r] = mn;
            O[0][r] *= fac; O[1][r] *= fac; O[2][r] *= fac; O[3][r] *= fac;
        }

        // PV from vr (P via same-wave LDS relayout)
        bf16x8 pf0 = *(const bf16x8*)&P_lds[lc * 72 + lg * 8];
        bf16x8 pf1 = *(const bf16x8*)&P_lds[lc * 72 + 32 + lg * 8];
#pragma unroll
        for (int df = 0; df < 4; ++df) {
            O[df] = __builtin_amdgcn_mfma_f32_16x16x32_bf16(pf0, vr[df * 2],     O[df], 0, 0, 0);
            O[df] = __builtin_amdgcn_mfma_f32_16x16x32_bf16(pf1, vr[df * 2 + 1], O[df], 0, 0, 0);
        }
        // prefetch V for t+1 (hides under next QK^T + softmax)
        if (t + 1 < nt) {
            const int kb0n = kb0 + 64;
#pragma unroll
            for (int df = 0; df < 4; ++df) {
                const unsigned short* vp = &Vt[((size_t)(b * 64 + df * 16 + lc)) * SEQ + kb0n];
                vr[df * 2]     = *(const bf16x8*)&vp[lg * 8];
                vr[df * 2 + 1] = *(const bf16x8*)&vp[32 + lg * 8];
            }
        }
    }

    const int slot = (b * 128 + qt) * 4 + ch;
    float* Op = O_part + (size_t)slot * 1024;
#pragma unroll
    for (int df = 0; df < 4; ++df)
#pragma unroll
        for (int r = 0; r < 4; ++r)
            Op[(lg * 4 + r) * 64 + df * 16 + lc] = O[df][r];
    if (lc == 0) {
#pragma unroll
        for (int r = 0; r < 4; ++r) {
            ml[slot * 32 + lg * 4 + r]      = m[r];
            ml[slot * 32 + 16 + lg * 4 + r] = l[r];
        }
    }
}

// ---------------------------------------------------------------------------
// Kernel 4: merge chunk partials -> final output (f32).
// ---------------------------------------------------------------------------
__global__ __launch_bounds__(256) void attn_merge(
    const float* __restrict__ O_part, const float* __restrict__ ml,
    float* __restrict__ out)
{
    int idx = blockIdx.x * 256 + threadIdx.x;   // 262144 threads, 2 f32 each
    int row = idx >> 5;
    int d0  = (idx & 31) * 2;
    int b = row >> 11, seq = row & 2047;
    int qt = seq >> 4, rl = seq & 15;
    int nc = ((qt * 16 + 15) >> 9) + 1;         // active chunks, 1..4
    int sb = (b * 128 + qt) * 4;

    float M = -1e30f;
    for (int c = 0; c < nc; ++c) M = fmaxf(M, ml[(sb + c) * 32 + rl]);
    float L = 0.f, o0 = 0.f, o1 = 0.f;
    for (int c = 0; c < nc; ++c) {
        float e = __expf(ml[(sb + c) * 32 + rl] - M);
        L += e * ml[(sb + c) * 32 + 16 + rl];
        const float* Op = O_part + (size_t)(sb + c) * 1024 + rl * 64 + d0;
        o0 += e * Op[0];
        o1 += e * Op[1];
    }
    float inv = 1.f / L;
    *(float2*)&out[(size_t)row * 64 + d0] = make_float2(o0 * inv, o1 * inv);
}

// ---------------------------------------------------------------------------
extern "C" void kernel_launch(void* const* d_in, const int* in_sizes, int n_in,
                              void* d_out, int out_size, void* d_ws, size_t ws_size,
                              hipStream_t stream)
{
    (void)in_sizes; (void)n_in; (void)out_size; (void)ws_size;

    const float* x  = (const float*)d_in[0];
    const float* Wq = (const float*)d_in[1];
    const float* bq = (const float*)d_in[2];
    const float* Wk = (const float*)d_in[3];
    const float* bk = (const float*)d_in[4];
    const float* Wv = (const float*)d_in[5];
    const float* bv = (const float*)d_in[6];
    float* out = (float*)d_out;

    // workspace layout (bytes):
    // Wb 393216 | qb 1M | kb 1M | Vt 1M | ml 262144 | O_part 8M  (~12.2 MB)
    char* ws = (char*)d_ws;
    unsigned short* Wb = (unsigned short*)(ws);
    unsigned short* qb = (unsigned short*)(ws + 393216);
    unsigned short* kb = (unsigned short*)(ws + 393216 + 1048576);
    unsigned short* Vt = (unsigned short*)(ws + 393216 + 2 * 1048576);
    float*          ml = (float*)(ws + 393216 + 3 * 1048576);
    float*      O_part = (float*)(ws + 393216 + 3 * 1048576 + 262144);

    w_pack<<<48, 256, 0, stream>>>(Wq, Wk, Wv, Wb);
    qkv_proj_mfma<<<512, 192, 0, stream>>>(x, Wb, bq, bk, bv, qb, kb, Vt);
    attn_partial<<<dim3(128, 4, 4), 64, 0, stream>>>(qb, kb, Vt, O_part, ml);
    attn_merge<<<1024, 256, 0, stream>>>(O_part, ml, out);
}

// Round 11
// 140.644 us; speedup vs baseline: 1.3297x; 1.1517x over previous
//
#include <hip/hip_runtime.h>
#include <math.h>

#define D_MODEL 1024
#define SEQ     2048
#define BATCH   4
#define NROWS   (BATCH * SEQ)   // 8192

typedef short bf16x8 __attribute__((ext_vector_type(8)));
typedef float f32x4  __attribute__((ext_vector_type(4)));

// f32 -> bf16 round-to-nearest-even
static __device__ __forceinline__ unsigned short f2bf(float f) {
    unsigned int x = __float_as_uint(f);
    x += 0x7FFFu + ((x >> 16) & 1u);
    return (unsigned short)(x >> 16);
}

// ---------------------------------------------------------------------------
// Kernel 1: pack W -> Wb[192][1024] bf16, coalesced reads + LDS transpose.
// ---------------------------------------------------------------------------
__global__ __launch_bounds__(256) void w_pack(
    const float* __restrict__ Wq, const float* __restrict__ Wk,
    const float* __restrict__ Wv, unsigned short* __restrict__ Wb)
{
    __shared__ float st[64][68];
    const int mat = blockIdx.x >> 4;
    const int k0  = (blockIdx.x & 15) * 64;
    const float* W = (mat == 0) ? Wq : (mat == 1) ? Wk : Wv;
    const int t  = threadIdx.x;
    const int kr = t >> 2, cs = (t & 3) * 16;
#pragma unroll
    for (int i = 0; i < 4; ++i)
        *(float4*)&st[kr][cs + i * 4] = *(const float4*)&W[(size_t)(k0 + kr) * 64 + cs + i * 4];
    __syncthreads();
    const int c = t >> 2, ks = (t & 3) * 16;
    unsigned short tmp[16];
#pragma unroll
    for (int j = 0; j < 16; ++j) tmp[j] = f2bf(st[ks + j][c]);
    *(uint4*)&Wb[(size_t)(mat * 64 + c) * D_MODEL + k0 + ks]     = *(uint4*)&tmp[0];
    *(uint4*)&Wb[(size_t)(mat * 64 + c) * D_MODEL + k0 + ks + 8] = *(uint4*)&tmp[8];
}

// ---------------------------------------------------------------------------
// Kernel 2: QKV projection via MFMA.  BM=64, BN=96, BK=64.
// grid (128, 2) x 256 thr (4 waves 2x2; wave tile 32x48 = 2x3 frags).
// __launch_bounds__(256, 1): VGPR budget up to 512 so the 7 staged loads
// (4x float4 A + 3x uint4 B) stay live and issue in parallel.
// Loop: {barrA; ds_write(t); barrB; issue loads(t+1); compute(t)} -- prefetch
// is issued after the last barrier of the iteration, so its latency hides
// under compute and is only collected at the next iteration's barrA.
// Epilogue: acc -> f32 LDS stage -> dense bf16 stores (V transposed).
// ---------------------------------------------------------------------------
__global__ __launch_bounds__(256, 1) void qkv_proj_mfma(
    const float* __restrict__ x, const unsigned short* __restrict__ Wb,
    const float* __restrict__ bq, const float* __restrict__ bk,
    const float* __restrict__ bv,
    unsigned short* __restrict__ qb, unsigned short* __restrict__ kb,
    unsigned short* __restrict__ Vt)
{
    __shared__ float smem[6400];                       // 25.6 KB, reused
    unsigned short* A_lds = (unsigned short*)smem;     // [64][72]
    unsigned short* B_lds = A_lds + 64 * 72;           // [96][72]

    const int tid  = threadIdx.x;
    const int wid  = tid >> 6;
    const int lane = tid & 63;
    const int wr   = wid >> 1;          // 0..1 row half
    const int wc   = wid & 1;           // 0..1 col half
    const int lg   = lane >> 4;         // 0..3
    const int lc   = lane & 15;         // 0..15
    const int m0   = blockIdx.x * 64;
    const int n0   = blockIdx.y * 96;
    const int by   = blockIdx.y;

    f32x4 acc[2][3];
#pragma unroll
    for (int mf = 0; mf < 2; ++mf)
#pragma unroll
        for (int nf = 0; nf < 3; ++nf) acc[mf][nf] = (f32x4){0.f, 0.f, 0.f, 0.f};

    // staging map: A rows arow0/arow0+32, slot ac8; B rows brow0+32i, slot bc8
    const int arow0 = tid >> 3, ac8 = tid & 7;   // A: 64 rows x 8 slots(16B)
    const int brow0 = tid >> 3, bc8 = tid & 7;   // B: 96 rows x 8 slots(16B)

    float4 a0[2], a1[2];
    uint4  brg[3];

    {   // prologue: k0 = 0
#pragma unroll
        for (int i = 0; i < 2; ++i) {
            const float* ap = &x[(size_t)(m0 + arow0 + 32 * i) * D_MODEL + ac8 * 8];
            a0[i] = *(const float4*)ap;
            a1[i] = *(const float4*)(ap + 4);
        }
#pragma unroll
        for (int i = 0; i < 3; ++i)
            brg[i] = *(const uint4*)&Wb[(size_t)(n0 + brow0 + 32 * i) * D_MODEL + bc8 * 8];
    }

    for (int it = 0; it < 16; ++it) {
        __syncthreads();                 // barrA: LDS free; collects loads(t)
#pragma unroll
        for (int i = 0; i < 2; ++i) {
            unsigned int w0 = f2bf(a0[i].x) | ((unsigned)f2bf(a0[i].y) << 16);
            unsigned int w1 = f2bf(a0[i].z) | ((unsigned)f2bf(a0[i].w) << 16);
            unsigned int w2 = f2bf(a1[i].x) | ((unsigned)f2bf(a1[i].y) << 16);
            unsigned int w3 = f2bf(a1[i].z) | ((unsigned)f2bf(a1[i].w) << 16);
            *(uint4*)&A_lds[(arow0 + 32 * i) * 72 + ac8 * 8] = make_uint4(w0, w1, w2, w3);
        }
#pragma unroll
        for (int i = 0; i < 3; ++i)
            *(uint4*)&B_lds[(brow0 + 32 * i) * 72 + bc8 * 8] = brg[i];
        __syncthreads();                 // barrB: LDS ready (no loads in flight)

        if (it < 15) {                   // issue loads(t+1): hide under compute
            const int k0 = (it + 1) * 64;
#pragma unroll
            for (int i = 0; i < 2; ++i) {
                const float* ap = &x[(size_t)(m0 + arow0 + 32 * i) * D_MODEL + k0 + ac8 * 8];
                a0[i] = *(const float4*)ap;
                a1[i] = *(const float4*)(ap + 4);
            }
#pragma unroll
            for (int i = 0; i < 3; ++i)
                brg[i] = *(const uint4*)&Wb[(size_t)(n0 + brow0 + 32 * i) * D_MODEL + k0 + bc8 * 8];
        }

#pragma unroll
        for (int kk = 0; kk < 2; ++kk) {
            bf16x8 af[2], bfr[3];
#pragma unroll
            for (int mf = 0; mf < 2; ++mf)
                af[mf] = *(const bf16x8*)&A_lds[(wr * 32 + mf * 16 + lc) * 72 + kk * 32 + lg * 8];
#pragma unroll
            for (int nf = 0; nf < 3; ++nf)
                bfr[nf] = *(const bf16x8*)&B_lds[(wc * 48 + nf * 16 + lc) * 72 + kk * 32 + lg * 8];
#pragma unroll
            for (int mf = 0; mf < 2; ++mf)
#pragma unroll
                for (int nf = 0; nf < 3; ++nf)
                    acc[mf][nf] = __builtin_amdgcn_mfma_f32_16x16x32_bf16(
                        af[mf], bfr[nf], acc[mf][nf], 0, 0, 0);
        }
    }

    // ---- epilogue: stage acc (f32) in LDS, then dense writes ----
    __syncthreads();                     // all compute done; reuse LDS
    float* st = smem;                    // [64][100]
#pragma unroll
    for (int mf = 0; mf < 2; ++mf)
#pragma unroll
        for (int nf = 0; nf < 3; ++nf)
#pragma unroll
            for (int r = 0; r < 4; ++r)
                st[(wr * 32 + mf * 16 + lg * 4 + r) * 100 + wc * 48 + nf * 16 + lc] = acc[mf][nf][r];
    __syncthreads();

    unsigned short tmp[16];
    if (by == 0) {
        // q: local cols 0..63
        {
            const int row = tid >> 2, c16 = (tid & 3) * 16;
#pragma unroll
            for (int j = 0; j < 16; ++j)
                tmp[j] = f2bf((st[row * 100 + c16 + j] + bq[c16 + j]) * 0.125f);
            unsigned short* dst = &qb[(size_t)(m0 + row) * 64 + c16];
            *(uint4*)dst       = *(uint4*)&tmp[0];
            *(uint4*)(dst + 8) = *(uint4*)&tmp[8];
        }
        // k cols 0..31: local cols 64..95
        if (tid < 128) {
            const int row = tid >> 1, c16 = (tid & 1) * 16;
#pragma unroll
            for (int j = 0; j < 16; ++j)
                tmp[j] = f2bf(st[row * 100 + 64 + c16 + j] + bk[c16 + j]);
            unsigned short* dst = &kb[(size_t)(m0 + row) * 64 + c16];
            *(uint4*)dst       = *(uint4*)&tmp[0];
            *(uint4*)(dst + 8) = *(uint4*)&tmp[8];
        }
    } else {
        // k cols 32..63: local cols 0..31
        if (tid < 128) {
            const int row = tid >> 1, c16 = (tid & 1) * 16;
#pragma unroll
            for (int j = 0; j < 16; ++j)
                tmp[j] = f2bf(st[row * 100 + c16 + j] + bk[32 + c16 + j]);
            unsigned short* dst = &kb[(size_t)(m0 + row) * 64 + 32 + c16];
            *(uint4*)dst       = *(uint4*)&tmp[0];
            *(uint4*)(dst + 8) = *(uint4*)&tmp[8];
        }
        // v: local cols 32..95 -> Vt[d][seq] transposed, dense in seq
        {
            const int d = tid >> 2, s16 = (tid & 3) * 16;
            const float bs = bv[d];
#pragma unroll
            for (int j = 0; j < 16; ++j)
                tmp[j] = f2bf(st[(s16 + j) * 100 + 32 + d] + bs);
            const int bb = m0 >> 11, seq0 = m0 & 2047;
            unsigned short* dst = &Vt[((size_t)(bb * 64 + d)) * SEQ + seq0 + s16];
            *(uint4*)dst       = *(uint4*)&tmp[0];
            *(uint4*)(dst + 8) = *(uint4*)&tmp[8];
        }
    }
}

// ---------------------------------------------------------------------------
// Kernel 3: causal flash attention partials — single wave, no barriers,
// direct-global K/V frags with cross-tile register prefetch.
// __launch_bounds__(64, 2): 256-VGPR budget so kr[8]+vr[8]+acc stay live.
// grid (qt 0..127, ch 0..3, b 0..3), 64 thr.
// ---------------------------------------------------------------------------
__global__ __launch_bounds__(64, 2) void attn_partial(
    const unsigned short* __restrict__ qb, const unsigned short* __restrict__ kb,
    const unsigned short* __restrict__ Vt,
    float* __restrict__ O_part, float* __restrict__ ml)
{
    __shared__ unsigned short P_lds[16 * 72];

    const int qt = blockIdx.x;
    const int ch = blockIdx.y;
    const int b  = blockIdx.z;
    const int lane = threadIdx.x;
    const int lg = lane >> 4, lc = lane & 15;

    int nt = ((qt * 16 + 15 - ch * 512) >> 6) + 1;
    if (nt > 8) nt = 8;
    if (nt <= 0) return;                       // block-uniform exit

    const size_t qrow = (size_t)(b * SEQ + qt * 16 + lc);
    bf16x8 qf0 = *(const bf16x8*)&qb[qrow * 64 + lg * 8];
    bf16x8 qf1 = *(const bf16x8*)&qb[qrow * 64 + 32 + lg * 8];

    f32x4 O[4];
#pragma unroll
    for (int df = 0; df < 4; ++df) O[df] = (f32x4){0.f, 0.f, 0.f, 0.f};
    float m[4] = {-1e30f, -1e30f, -1e30f, -1e30f};
    float l[4] = {0.f, 0.f, 0.f, 0.f};

    const int rowbase = qt * 16 + lg * 4;

    bf16x8 kr[8], vr[8];
    {   // prologue: tile 0 K+V
        const int kb0 = ch * 512;
#pragma unroll
        for (int kf = 0; kf < 4; ++kf) {
            const unsigned short* kp = &kb[((size_t)(b * SEQ + kb0 + kf * 16 + lc)) * 64];
            kr[kf * 2]     = *(const bf16x8*)&kp[lg * 8];
            kr[kf * 2 + 1] = *(const bf16x8*)&kp[32 + lg * 8];
            const unsigned short* vp = &Vt[((size_t)(b * 64 + kf * 16 + lc)) * SEQ + kb0];
            vr[kf * 2]     = *(const bf16x8*)&vp[lg * 8];
            vr[kf * 2 + 1] = *(const bf16x8*)&vp[32 + lg * 8];
        }
    }

    for (int t = 0; t < nt; ++t) {
        const int kb0 = ch * 512 + t * 64;

        // QK^T from kr
        f32x4 s[4];
#pragma unroll
        for (int kf = 0; kf < 4; ++kf) {
            f32x4 z = (f32x4){0.f, 0.f, 0.f, 0.f};
            z = __builtin_amdgcn_mfma_f32_16x16x32_bf16(qf0, kr[kf * 2], z, 0, 0, 0);
            s[kf] = __builtin_amdgcn_mfma_f32_16x16x32_bf16(qf1, kr[kf * 2 + 1], z, 0, 0, 0);
        }
        // prefetch K for t+1 (hides under softmax + PV)
        if (t + 1 < nt) {
            const int kb0n = kb0 + 64;
#pragma unroll
            for (int kf = 0; kf < 4; ++kf) {
                const unsigned short* kp = &kb[((size_t)(b * SEQ + kb0n + kf * 16 + lc)) * 64];
                kr[kf * 2]     = *(const bf16x8*)&kp[lg * 8];
                kr[kf * 2 + 1] = *(const bf16x8*)&kp[32 + lg * 8];
            }
        }

        // online softmax; D-layout: key = kb0 + kf*16 + lc, row = rowbase + r
#pragma unroll
        for (int r = 0; r < 4; ++r) {
            float tm = -1e30f;
#pragma unroll
            for (int kf = 0; kf < 4; ++kf) {
                float sv = s[kf][r];
                if (kb0 + kf * 16 + lc > rowbase + r) sv = -1e30f;
                s[kf][r] = sv;
                tm = fmaxf(tm, sv);
            }
            tm = fmaxf(tm, __shfl_xor(tm, 1));
            tm = fmaxf(tm, __shfl_xor(tm, 2));
            tm = fmaxf(tm, __shfl_xor(tm, 4));
            tm = fmaxf(tm, __shfl_xor(tm, 8));
            float mn  = fmaxf(m[r], tm);
            float fac = __expf(m[r] - mn);
            float ts  = 0.f;
#pragma unroll
            for (int kf = 0; kf < 4; ++kf) {
                float p = __expf(s[kf][r] - mn);
                ts += p;
                P_lds[(lg * 4 + r) * 72 + kf * 16 + lc] = f2bf(p);
            }
            ts += __shfl_xor(ts, 1);
            ts += __shfl_xor(ts, 2);
            ts += __shfl_xor(ts, 4);
            ts += __shfl_xor(ts, 8);
            l[r] = l[r] * fac + ts;
            m[r] = mn;
            O[0][r] *= fac; O[1][r] *= fac; O[2][r] *= fac; O[3][r] *= fac;
        }

        // PV from vr (P via same-wave LDS relayout)
        bf16x8 pf0 = *(const bf16x8*)&P_lds[lc * 72 + lg * 8];
        bf16x8 pf1 = *(const bf16x8*)&P_lds[lc * 72 + 32 + lg * 8];
#pragma unroll
        for (int df = 0; df < 4; ++df) {
            O[df] = __builtin_amdgcn_mfma_f32_16x16x32_bf16(pf0, vr[df * 2],     O[df], 0, 0, 0);
            O[df] = __builtin_amdgcn_mfma_f32_16x16x32_bf16(pf1, vr[df * 2 + 1], O[df], 0, 0, 0);
        }
        // prefetch V for t+1 (hides under next QK^T + softmax)
        if (t + 1 < nt) {
            const int kb0n = kb0 + 64;
#pragma unroll
            for (int df = 0; df < 4; ++df) {
                const unsigned short* vp = &Vt[((size_t)(b * 64 + df * 16 + lc)) * SEQ + kb0n];
                vr[df * 2]     = *(const bf16x8*)&vp[lg * 8];
                vr[df * 2 + 1] = *(const bf16x8*)&vp[32 + lg * 8];
            }
        }
    }

    const int slot = (b * 128 + qt) * 4 + ch;
    float* Op = O_part + (size_t)slot * 1024;
#pragma unroll
    for (int df = 0; df < 4; ++df)
#pragma unroll
        for (int r = 0; r < 4; ++r)
            Op[(lg * 4 + r) * 64 + df * 16 + lc] = O[df][r];
    if (lc == 0) {
#pragma unroll
        for (int r = 0; r < 4; ++r) {
            ml[slot * 32 + lg * 4 + r]      = m[r];
            ml[slot * 32 + 16 + lg * 4 + r] = l[r];
        }
    }
}

// ---------------------------------------------------------------------------
// Kernel 4: merge chunk partials -> final output (f32).
// ---------------------------------------------------------------------------
__global__ __launch_bounds__(256) void attn_merge(
    const float* __restrict__ O_part, const float* __restrict__ ml,
    float* __restrict__ out)
{
    int idx = blockIdx.x * 256 + threadIdx.x;   // 262144 threads, 2 f32 each
    int row = idx >> 5;
    int d0  = (idx & 31) * 2;
    int b = row >> 11, seq = row & 2047;
    int qt = seq >> 4, rl = seq & 15;
    int nc = ((qt * 16 + 15) >> 9) + 1;         // active chunks, 1..4
    int sb = (b * 128 + qt) * 4;

    float M = -1e30f;
    for (int c = 0; c < nc; ++c) M = fmaxf(M, ml[(sb + c) * 32 + rl]);
    float L = 0.f, o0 = 0.f, o1 = 0.f;
    for (int c = 0; c < nc; ++c) {
        float e = __expf(ml[(sb + c) * 32 + rl] - M);
        L += e * ml[(sb + c) * 32 + 16 + rl];
        const float* Op = O_part + (size_t)(sb + c) * 1024 + rl * 64 + d0;
        o0 += e * Op[0];
        o1 += e * Op[1];
    }
    float inv = 1.f / L;
    *(float2*)&out[(size_t)row * 64 + d0] = make_float2(o0 * inv, o1 * inv);
}

// ---------------------------------------------------------------------------
extern "C" void kernel_launch(void* const* d_in, const int* in_sizes, int n_in,
                              void* d_out, int out_size, void* d_ws, size_t ws_size,
                              hipStream_t stream)
{
    (void)in_sizes; (void)n_in; (void)out_size; (void)ws_size;

    const float* x  = (const float*)d_in[0];
    const float* Wq = (const float*)d_in[1];
    const float* bq = (const float*)d_in[2];
    const float* Wk = (const float*)d_in[3];
    const float* bk = (const float*)d_in[4];
    const float* Wv = (const float*)d_in[5];
    const float* bv = (const float*)d_in[6];
    float* out = (float*)d_out;

    // workspace layout (bytes):
    // Wb 393216 | qb 1M | kb 1M | Vt 1M | ml 262144 | O_part 8M  (~12.2 MB)
    char* ws = (char*)d_ws;
    unsigned short* Wb = (unsigned short*)(ws);
    unsigned short* qb = (unsigned short*)(ws + 393216);
    unsigned short* kb = (unsigned short*)(ws + 393216 + 1048576);
    unsigned short* Vt = (unsigned short*)(ws + 393216 + 2 * 1048576);
    float*          ml = (float*)(ws + 393216 + 3 * 1048576);
    float*      O_part = (float*)(ws + 393216 + 3 * 1048576 + 262144);

    w_pack<<<48, 256, 0, stream>>>(Wq, Wk, Wv, Wb);
    qkv_proj_mfma<<<dim3(128, 2), 256, 0, stream>>>(x, Wb, bq, bk, bv, qb, kb, Vt);
    attn_partial<<<dim3(128, 4, 4), 64, 0, stream>>>(qb, kb, Vt, O_part, ml);
    attn_merge<<<1024, 256, 0, stream>>>(O_part, ml, out);
}